// Round 1
// baseline (76.583 us; speedup 1.0000x reference)
//
#include <hip/hip_runtime.h>
#include <math.h>

#define NROWS   96
#define DIM     768
#define THRESH  0.3f
#define NPAIR   4560            // 96*95/2
#define PTOT    9120            // 2*NPAIR
#define QTOT    9216            // 96*96
#define NDOT    18336           // 2*NPAIR + QTOT
#define SEG     576             // QTOT / 16
#define NSEG    16

// ws layout (floats): invn[192] | pos[9120] | neg[9216] | (double) acc
// total = 18528 floats = 74112 bytes, then 8 bytes for acc.

// ---------------- Kernel A: inverse row norms + zero accumulator -------------
__global__ __launch_bounds__(256) void invnorm_kernel(
    const float* __restrict__ stereos, const float* __restrict__ astereos,
    float* __restrict__ invn, double* __restrict__ acc)
{
    int row = blockIdx.x;              // 0..191
    const float* src = (row < NROWS) ? (stereos + row * DIM)
                                     : (astereos + (row - NROWS) * DIM);
    int tid = threadIdx.x;
    float v0 = src[tid], v1 = src[tid + 256], v2 = src[tid + 512];
    float ss = v0 * v0 + v1 * v1 + v2 * v2;
    for (int off = 32; off; off >>= 1) ss += __shfl_down(ss, off);
    __shared__ float red[4];
    int wave = tid >> 6, lane = tid & 63;
    if (lane == 0) red[wave] = ss;
    __syncthreads();
    if (tid == 0) {
        float tot = red[0] + red[1] + red[2] + red[3];
        invn[row] = 1.0f / fmaxf(sqrtf(tot), 1e-8f);
        if (row == 0) *acc = 0.0;      // zero hinge accumulator (ws is poisoned)
    }
}

// ---------------- Kernel B: all similarity dot products (wave per dot) -------
__global__ __launch_bounds__(256) void sims_kernel(
    const float* __restrict__ stereos, const float* __restrict__ astereos,
    const float* __restrict__ invn, float* __restrict__ pos,
    float* __restrict__ neg)
{
    int wave = threadIdx.x >> 6;
    int lane = threadIdx.x & 63;
    int d = blockIdx.x * 4 + wave;     // dot index, 0..18335
    if (d >= NDOT) return;

    const float *va, *vb;
    float scale;
    float* outp;
    if (d < 2 * NPAIR) {
        int t = d;
        const float* base;
        const float* inb;
        if (d < NPAIR) { base = stereos;  inb = invn; }
        else           { t = d - NPAIR; base = astereos; inb = invn + NROWS; }
        // triangular decode: find i with B(i) <= t < B(i+1), B(i)=i*(191-i)/2
        int i = (int)((191.0 - sqrt(36481.0 - 8.0 * (double)t)) * 0.5);
        if (i < 0) i = 0;
        if (i > 94) i = 94;
        while (i > 0 && (i * (191 - i)) / 2 > t) --i;
        while (((i + 1) * (190 - i)) / 2 <= t) ++i;
        int j = t - (i * (191 - i)) / 2 + i + 1;
        va = base + i * DIM;
        vb = base + j * DIM;
        scale = inb[i] * inb[j];
        outp = pos + d;
    } else {
        int t = d - 2 * NPAIR;
        int i = t / NROWS, j = t - i * NROWS;
        va = astereos + i * DIM;
        vb = stereos + j * DIM;
        scale = invn[NROWS + i] * invn[j];
        outp = neg + t;
    }

    float accd = 0.f;
#pragma unroll
    for (int k = 0; k < 3; k++) {       // DIM/4 = 192 float4s, 64 lanes -> 3 each
        float4 a = ((const float4*)va)[lane + 64 * k];
        float4 b = ((const float4*)vb)[lane + 64 * k];
        accd += a.x * b.x + a.y * b.y + a.z * b.z + a.w * b.w;
    }
    for (int off = 32; off; off >>= 1) accd += __shfl_down(accd, off);
    if (lane == 0) *outp = accd * scale;
}

// ---------------- Kernel C: hinge sum over P x Q via abs identity ------------
// sum_q max(0, n_q - c) = 0.5 * (segSum - cnt*c + sum_q |n_q - c|),  c = p - T
__global__ __launch_bounds__(256) void hinge_kernel(
    const float* __restrict__ pos, const float* __restrict__ neg,
    double* __restrict__ acc)
{
    __shared__ __align__(16) float lneg[SEG];
    __shared__ float red[4];
    int tid = threadIdx.x;
    int wave = tid >> 6, lane = tid & 63;

    const float* segp = neg + blockIdx.y * SEG;
    float lsum = 0.f;
    for (int k = tid; k < SEG; k += 256) {
        float v = segp[k];
        lneg[k] = v;
        lsum += v;
    }
    for (int off = 32; off; off >>= 1) lsum += __shfl_down(lsum, off);
    if (lane == 0) red[wave] = lsum;
    __syncthreads();
    float segSum = red[0] + red[1] + red[2] + red[3];

    int p = blockIdx.x * 256 + tid;
    float thisSum = 0.f;
    if (p < PTOT) {
        float c = pos[p] - THRESH;
        float aabs = 0.f;
        const float4* l4 = (const float4*)lneg;
#pragma unroll 4
        for (int k = 0; k < SEG / 4; k++) {
            float4 n = l4[k];
            aabs += fabsf(n.x - c) + fabsf(n.y - c) +
                    fabsf(n.z - c) + fabsf(n.w - c);
        }
        thisSum = 0.5f * (segSum - (float)SEG * c + aabs);
    }
    for (int off = 32; off; off >>= 1) thisSum += __shfl_down(thisSum, off);
    __syncthreads();                    // red[] reuse
    if (lane == 0) red[wave] = thisSum;
    __syncthreads();
    if (tid == 0) {
        double b = (double)(red[0] + red[1] + red[2] + red[3]);
        atomicAdd(acc, b);
    }
}

// ---------------- Kernel D: finalize ----------------------------------------
__global__ void finalize_kernel(const double* __restrict__ acc,
                                float* __restrict__ out)
{
    out[0] = (float)(acc[0] / (double)((long long)PTOT * (long long)QTOT));
}

extern "C" void kernel_launch(void* const* d_in, const int* in_sizes, int n_in,
                              void* d_out, int out_size, void* d_ws, size_t ws_size,
                              hipStream_t stream)
{
    const float* stereos  = (const float*)d_in[0];
    const float* astereos = (const float*)d_in[1];

    float* invn = (float*)d_ws;
    float* pos  = invn + 192;
    float* neg  = pos + PTOT;
    double* acc = (double*)((char*)d_ws + (size_t)(192 + PTOT + QTOT) * sizeof(float));

    invnorm_kernel<<<192, 256, 0, stream>>>(stereos, astereos, invn, acc);
    sims_kernel<<<NDOT / 4, 256, 0, stream>>>(stereos, astereos, invn, pos, neg);
    hinge_kernel<<<dim3((PTOT + 255) / 256, NSEG), 256, 0, stream>>>(pos, neg, acc);
    finalize_kernel<<<1, 1, 0, stream>>>(acc, (float*)d_out);
}